// Round 4
// baseline (447.205 us; speedup 1.0000x reference)
//
#include <hip/hip_runtime.h>

#define NTOK 160
#define EDIM 256
#define HH 4
#define NNR 25600          // NTOK*NTOK rows
#define PC 784             // packed projection cols
#define YBC 768            // bf16 matmul cols of Y
#define SCALEF 0.125f
#define LNEPS 1e-5f

// ---- workspace layout (float offsets) ----
#define OFF_ELN 0LL                      // bf16 [NNR][256]
#define OFF_YBF (OFF_ELN + 3276800LL)    // bf16 [NNR][768]
#define OFF_YEG (OFF_YBF + 9830400LL)    // fp32 [NNR][16]
#define OFF_WPT (OFF_YEG + 409600LL)     // bf16 [784][256]
#define OFF_BP  (OFF_WPT + 100352LL)     // fp32 [784]
#define OFF_WOT (OFF_BP  + 800LL)        // bf16 [256][512]
#define OFF_BGI (OFF_WOT + 65536LL)      // float2 [4][NNR]
#define OFF_BGO (OFF_BGI + 204800LL)     // float2 [4][NNR]
#define OFF_VAB (OFF_BGO + 204800LL)     // bf16 [NNR][512]
// end = OFF_VAB + 6,553,600 = 20,646,688 floats (~83 MiB)

typedef short bf16x8 __attribute__((ext_vector_type(8)));
typedef unsigned short u16x8 __attribute__((ext_vector_type(8)));
typedef unsigned short u16x4 __attribute__((ext_vector_type(4)));
typedef float f32x4 __attribute__((ext_vector_type(4)));

__device__ __forceinline__ unsigned short bf16_rne(float f) {
  unsigned int u = __float_as_uint(f);
  u += 0x7FFFu + ((u >> 16) & 1u);
  return (unsigned short)(u >> 16);
}

__device__ __forceinline__ float wave_sum(float v) {
  #pragma unroll
  for (int o = 1; o < 64; o <<= 1) v += __shfl_xor(v, o, 64);
  return v;
}

// ---------------- pack: WpT[784][256] bf16, bp[784] f32, WoT[256][512] bf16 ----
// packed col map n: [0,256) Qin(h-major, *SCALE) | [256,320) Kin | [320,384) Vin |
// [384,640) Qout | [640,704) Kout | [704,768) Vout |
// [768,772) E_in | [772,776) G_in | [776,780) E_out | [780,784) G_out
__device__ __forceinline__ void col_map(int n, const float* const* W, const float* const* bia,
                                        const float** Wsel, const float** bsel,
                                        int* col, int* ld, float* scale) {
  *scale = 1.f;
  if (n < 256)      { *Wsel = W[0]; *bsel = bia[0]; *col = (n&63)*4 + (n>>6); *ld = 256; *scale = SCALEF; }
  else if (n < 320) { *Wsel = W[1]; *bsel = bia[1]; *col = n - 256;        *ld = 128; }
  else if (n < 384) { *Wsel = W[1]; *bsel = bia[1]; *col = 64 + n - 320;   *ld = 128; }
  else if (n < 640) { int c2 = n - 384; *Wsel = W[3]; *bsel = bia[3]; *col = (c2&63)*4 + (c2>>6); *ld = 256; *scale = SCALEF; }
  else if (n < 704) { *Wsel = W[4]; *bsel = bia[4]; *col = n - 640;        *ld = 128; }
  else if (n < 768) { *Wsel = W[4]; *bsel = bia[4]; *col = 64 + n - 704;   *ld = 128; }
  else if (n < 772) { *Wsel = W[2]; *bsel = bia[2]; *col = n - 768;        *ld = 8; }
  else if (n < 776) { *Wsel = W[2]; *bsel = bia[2]; *col = 4 + n - 772;    *ld = 8; }
  else if (n < 780) { *Wsel = W[5]; *bsel = bia[5]; *col = n - 776;        *ld = 8; }
  else              { *Wsel = W[5]; *bsel = bia[5]; *col = 4 + n - 780;    *ld = 8; }
}

__global__ void pack_kernel(const float* __restrict__ Wq_in,  const float* __restrict__ bq_in,
                            const float* __restrict__ Wkv_in, const float* __restrict__ bkv_in,
                            const float* __restrict__ Weg_in, const float* __restrict__ beg_in,
                            const float* __restrict__ Wq_out, const float* __restrict__ bq_out,
                            const float* __restrict__ Wkv_out,const float* __restrict__ bkv_out,
                            const float* __restrict__ Weg_out,const float* __restrict__ beg_out,
                            const float* __restrict__ Wo,
                            unsigned short* __restrict__ WpT, float* __restrict__ bp,
                            unsigned short* __restrict__ WoT) {
  const float* W[6]  = {Wq_in, Wkv_in, Weg_in, Wq_out, Wkv_out, Weg_out};
  const float* bi[6] = {bq_in, bkv_in, beg_in, bq_out, bkv_out, beg_out};
  int idx = blockIdx.x * blockDim.x + threadIdx.x;
  if (idx < PC * 256) {
    int n = idx >> 8, k = idx & 255;
    const float *Ws, *bs; int col, ld; float sc;
    col_map(n, W, bi, &Ws, &bs, &col, &ld, &sc);
    WpT[idx] = bf16_rne(Ws[(long long)k * ld + col] * sc);
  } else if (idx < PC * 256 + PC) {
    int n = idx - PC * 256;
    const float *Ws, *bs; int col, ld; float sc;
    col_map(n, W, bi, &Ws, &bs, &col, &ld, &sc);
    bp[n] = bs[col] * sc;
  } else if (idx < PC * 256 + PC + 256 * 512) {
    int q = idx - (PC * 256 + PC);
    int n = q >> 9, kk = q & 511;
    int brn = kk >> 8, hh = (kk >> 6) & 3, dd = kk & 63;
    WoT[q] = bf16_rne(Wo[(long long)(dd * 8 + hh + 4 * brn) * 256 + n]);
  }
}

// ---------------- layernorm -> bf16: one wave per row ----------------
__global__ __launch_bounds__(256) void ln_kernel(const float* __restrict__ e,
                                                 const float* __restrict__ g,
                                                 const float* __restrict__ b,
                                                 unsigned short* __restrict__ elnbf) {
  int row  = blockIdx.x * 4 + (threadIdx.x >> 6);
  int lane = threadIdx.x & 63;
  float4 x = ((const float4*)(e + (long long)row * EDIM))[lane];
  float s = wave_sum(x.x + x.y + x.z + x.w);
  float mu = s * (1.f / EDIM);
  float d0 = x.x - mu, d1 = x.y - mu, d2 = x.z - mu, d3 = x.w - mu;
  float v = wave_sum(d0*d0 + d1*d1 + d2*d2 + d3*d3);
  float rs = rsqrtf(v * (1.f / EDIM) + LNEPS);
  float4 gg = ((const float4*)g)[lane], bb = ((const float4*)b)[lane];
  u16x4 y;
  y[0] = bf16_rne(d0 * rs * gg.x + bb.x);
  y[1] = bf16_rne(d1 * rs * gg.y + bb.y);
  y[2] = bf16_rne(d2 * rs * gg.z + bb.z);
  y[3] = bf16_rne(d3 * rs * gg.w + bb.w);
  *(u16x4*)&elnbf[(long long)row * EDIM + lane * 4] = y;
}

// ---------------- projection GEMM (MFMA): Y = eln @ Wp + bp ----------------
// grid (7 x 112 cols, 200 x 128 rows), 256 thr, K-step 64
__global__ __launch_bounds__(256) void proj_kernel(const unsigned short* __restrict__ Abf,
                                                   const unsigned short* __restrict__ WpT,
                                                   const float* __restrict__ bp,
                                                   unsigned short* __restrict__ Ybf,
                                                   float* __restrict__ Yeg) {
  __shared__ unsigned short As[128][72];
  __shared__ unsigned short Bs[112][72];
  const int n0 = blockIdx.x * 112;
  const int m0 = blockIdx.y * 128;
  const int t = threadIdx.x;
  const int lane = t & 63, w = t >> 6;
  const int quad = lane >> 4, l15 = lane & 15;
  f32x4 acc[2][7];
  #pragma unroll
  for (int a = 0; a < 2; ++a)
    #pragma unroll
    for (int c = 0; c < 7; ++c) acc[a][c] = (f32x4){0.f,0.f,0.f,0.f};
  for (int k0 = 0; k0 < 256; k0 += 64) {
    #pragma unroll
    for (int p = 0; p < 4; ++p) {
      int f = t + p * 256;
      int row = f >> 3, c = (f & 7) << 3;
      *(u16x8*)&As[row][c] = *(const u16x8*)&Abf[(long long)(m0 + row) * 256 + k0 + c];
    }
    #pragma unroll
    for (int p = 0; p < 4; ++p) {
      int f = t + p * 256;
      int row = f >> 3, c = (f & 7) << 3;
      if (row < 112)
        *(u16x8*)&Bs[row][c] = *(const u16x8*)&WpT[(long long)(n0 + row) * 256 + k0 + c];
    }
    __syncthreads();
    #pragma unroll
    for (int ks = 0; ks < 2; ++ks) {
      bf16x8 a0 = *(const bf16x8*)&As[w * 32 + l15][ks * 32 + quad * 8];
      bf16x8 a1 = *(const bf16x8*)&As[w * 32 + 16 + l15][ks * 32 + quad * 8];
      #pragma unroll
      for (int nt = 0; nt < 7; ++nt) {
        bf16x8 bfr = *(const bf16x8*)&Bs[nt * 16 + l15][ks * 32 + quad * 8];
        acc[0][nt] = __builtin_amdgcn_mfma_f32_16x16x32_bf16(a0, bfr, acc[0][nt], 0, 0, 0);
        acc[1][nt] = __builtin_amdgcn_mfma_f32_16x16x32_bf16(a1, bfr, acc[1][nt], 0, 0, 0);
      }
    }
    __syncthreads();
  }
  #pragma unroll
  for (int nt = 0; nt < 7; ++nt) {
    int col = n0 + nt * 16 + l15;
    float bias = bp[col];
    #pragma unroll
    for (int mt = 0; mt < 2; ++mt) {
      #pragma unroll
      for (int r = 0; r < 4; ++r) {
        long long row = m0 + w * 32 + mt * 16 + quad * 4 + r;
        float v = acc[mt][nt][r] + bias;
        if (col < YBC) Ybf[row * YBC + col] = bf16_rne(v);
        else           Yeg[row * 16 + (col - YBC)] = v;
      }
    }
  }
}

// ---------------- E/G precompute: float2 (bias, gate) planes [h][NNR] ----------------
__global__ void eg_kernel(const float* __restrict__ Yeg, const float* __restrict__ mask,
                          float2* __restrict__ bgIn, float2* __restrict__ bgOut) {
  int r = blockIdx.x * blockDim.x + threadIdx.x;
  if (r >= NNR) return;
  float m = mask[r];
  const float* yr = Yeg + (long long)r * 16;
  int i = r % NTOK, k = r / NTOK;
  long long rt = (long long)i * NTOK + k;
  #pragma unroll
  for (int h = 0; h < HH; ++h) {
    bgIn [h * NNR + r]  = make_float2(yr[h] + m,     1.f / (1.f + __expf(-(yr[4 + h] + m))));
    bgOut[h * NNR + rt] = make_float2(yr[8 + h] + m, 1.f / (1.f + __expf(-(yr[12 + h] + m))));
  }
}

// ---------------- attention: wave = head, 2 M-tiles/block. grid (5, 160, 2) ----------------
__global__ __launch_bounds__(256) void attn_kernel(const unsigned short* __restrict__ Ybf,
                                                   const float2* __restrict__ bgIn,
                                                   const float2* __restrict__ bgOut,
                                                   unsigned short* __restrict__ Vab) {
  __shared__ unsigned short Kl[160][72];       // [k_token][d]
  __shared__ unsigned short Vt[64][168];       // [d][k_token]
  __shared__ unsigned short Pl[HH][16][168];   // per-head probs (A-layout rows)
  const int i00 = blockIdx.x * 32;
  const int j   = blockIdx.y;
  const int br  = blockIdx.z;
  const int t   = threadIdx.x;
  const int kb = br ? 640 : 256, vb = kb + 64, qb = br ? 384 : 0;
  const float2* bg = br ? bgOut : bgIn;

  const int lane = t & 63, h = t >> 6;     // wave w == head h
  const int quad = lane >> 4, l15 = lane & 15;

  // ---- Q prefetch for both M-tiles (before staging barrier) ----
  const unsigned short* qp0 = &Ybf[((long long)(i00 + l15) * NTOK + j) * YBC + qb + h * 64 + quad * 8];
  const unsigned short* qp1 = qp0 + 16LL * NTOK * YBC;
  bf16x8 aq[2][2];
  aq[0][0] = *(const bf16x8*)qp0;  aq[0][1] = *(const bf16x8*)(qp0 + 32);
  aq[1][0] = *(const bf16x8*)qp1;  aq[1][1] = *(const bf16x8*)(qp1 + 32);

  // ---- stage K [160][64] ----
  for (int f = t; f < 160 * 8; f += 256) {
    int k = f >> 3, c = (f & 7) << 3;
    long long row = br ? ((long long)k * NTOK + j) : ((long long)j * NTOK + k);
    *(u16x8*)&Kl[k][c] = *(const u16x8*)&Ybf[row * YBC + kb + c];
  }
  // ---- stage V transposed [d][k] (rotated scalar writes) ----
  for (int f = t; f < 160 * 8; f += 256) {
    int k = f >> 3, g = f & 7, c = g << 3;
    long long row = br ? ((long long)k * NTOK + j) : ((long long)j * NTOK + k);
    u16x8 v = *(const u16x8*)&Ybf[row * YBC + vb + c];
    #pragma unroll
    for (int m = 0; m < 8; ++m) { int mm = (m + g) & 7; Vt[c + mm][k] = v[mm]; }
  }
  __syncthreads();

  for (int mt = 0; mt < 2; ++mt) {
    const int i0 = i00 + mt * 16;
    // ---- QK^T: S[i=quad*4+r][kt=n*16+l15] in registers ----
    f32x4 acc[10];
    #pragma unroll
    for (int n = 0; n < 10; ++n) acc[n] = (f32x4){0.f,0.f,0.f,0.f};
    #pragma unroll
    for (int n = 0; n < 10; ++n) {
      acc[n] = __builtin_amdgcn_mfma_f32_16x16x32_bf16(aq[mt][0], *(const bf16x8*)&Kl[n*16 + l15][quad*8],      acc[n], 0,0,0);
      acc[n] = __builtin_amdgcn_mfma_f32_16x16x32_bf16(aq[mt][1], *(const bf16x8*)&Kl[n*16 + l15][32 + quad*8], acc[n], 0,0,0);
    }
    // ---- softmax (sum-only; normalization deferred to PV output) ----
    float sum[4] = {0.f, 0.f, 0.f, 0.f};
    const float2* bgh = bg + (long long)h * NNR + (long long)i0 * NTOK;
    #pragma unroll
    for (int n = 0; n < 10; ++n) {
      #pragma unroll
      for (int r = 0; r < 4; ++r) {
        float2 b2 = bgh[(quad * 4 + r) * NTOK + n * 16 + l15];
        float q = __expf(acc[n][r] + b2.x);
        sum[r] += q;
        Pl[h][quad * 4 + r][n * 16 + l15] = bf16_rne(q * b2.y);
      }
    }
    #pragma unroll
    for (int r = 0; r < 4; ++r) {
      #pragma unroll
      for (int m = 1; m < 16; m <<= 1) sum[r] += __shfl_xor(sum[r], m, 64);
    }
    // ---- PV (wave-private Pl; no barrier needed) ----
    f32x4 o[4];
    #pragma unroll
    for (int d = 0; d < 4; ++d) o[d] = (f32x4){0.f,0.f,0.f,0.f};
    #pragma unroll
    for (int ks = 0; ks < 5; ++ks) {
      bf16x8 af = *(const bf16x8*)&Pl[h][l15][ks * 32 + quad * 8];
      #pragma unroll
      for (int d = 0; d < 4; ++d)
        o[d] = __builtin_amdgcn_mfma_f32_16x16x32_bf16(af, *(const bf16x8*)&Vt[d*16 + l15][ks*32 + quad*8], o[d], 0,0,0);
    }
    float inv[4];
    #pragma unroll
    for (int r = 0; r < 4; ++r) inv[r] = 1.f / sum[r];
    #pragma unroll
    for (int d = 0; d < 4; ++d)
      #pragma unroll
      for (int r = 0; r < 4; ++r)
        Vab[((long long)(i0 + quad*4 + r) * NTOK + j) * 512 + br*256 + h*64 + d*16 + l15] =
            bf16_rne(o[d][r] * inv[r]);
  }
}

// ---------------- output GEMM (MFMA): out = Va @ WoT^T + bo ----------------
// grid (2 x 128 cols, 400 x 64 rows), 256 thr, K-step 64
__global__ __launch_bounds__(256) void out_kernel(const unsigned short* __restrict__ Vab,
                                                  const unsigned short* __restrict__ WoT,
                                                  const float* __restrict__ bo,
                                                  float* __restrict__ out) {
  __shared__ unsigned short As[64][72];
  __shared__ unsigned short Bs[128][72];
  const int n0 = blockIdx.x * 128;
  const int m0 = blockIdx.y * 64;
  const int t = threadIdx.x;
  const int lane = t & 63, w = t >> 6;
  const int quad = lane >> 4, l15 = lane & 15;
  f32x4 acc[8];
  #pragma unroll
  for (int c = 0; c < 8; ++c) acc[c] = (f32x4){0.f,0.f,0.f,0.f};
  for (int k0 = 0; k0 < 512; k0 += 64) {
    #pragma unroll
    for (int p = 0; p < 2; ++p) {
      int f = t + p * 256;
      int row = f >> 3, c = (f & 7) << 3;
      *(u16x8*)&As[row][c] = *(const u16x8*)&Vab[(long long)(m0 + row) * 512 + k0 + c];
    }
    #pragma unroll
    for (int p = 0; p < 4; ++p) {
      int f = t + p * 256;
      int row = f >> 3, c = (f & 7) << 3;
      *(u16x8*)&Bs[row][c] = *(const u16x8*)&WoT[(long long)(n0 + row) * 512 + k0 + c];
    }
    __syncthreads();
    #pragma unroll
    for (int ks = 0; ks < 2; ++ks) {
      bf16x8 a0 = *(const bf16x8*)&As[w * 16 + l15][ks * 32 + quad * 8];
      #pragma unroll
      for (int nt = 0; nt < 8; ++nt) {
        bf16x8 bfr = *(const bf16x8*)&Bs[nt * 16 + l15][ks * 32 + quad * 8];
        acc[nt] = __builtin_amdgcn_mfma_f32_16x16x32_bf16(a0, bfr, acc[nt], 0, 0, 0);
      }
    }
    __syncthreads();
  }
  #pragma unroll
  for (int nt = 0; nt < 8; ++nt) {
    int col = n0 + nt * 16 + l15;
    float bias = bo[col];
    #pragma unroll
    for (int r = 0; r < 4; ++r) {
      long long row = m0 + w * 16 + quad * 4 + r;
      out[row * 256 + col] = acc[nt][r] + bias;
    }
  }
}

extern "C" void kernel_launch(void* const* d_in, const int* in_sizes, int n_in,
                              void* d_out, int out_size, void* d_ws, size_t ws_size,
                              hipStream_t stream) {
  const float* e       = (const float*)d_in[0];
  const float* mask    = (const float*)d_in[1];
  const float* ln_g    = (const float*)d_in[2];
  const float* ln_b    = (const float*)d_in[3];
  const float* Wq_in   = (const float*)d_in[4];
  const float* bq_in   = (const float*)d_in[5];
  const float* Wkv_in  = (const float*)d_in[6];
  const float* bkv_in  = (const float*)d_in[7];
  const float* Weg_in  = (const float*)d_in[8];
  const float* beg_in  = (const float*)d_in[9];
  const float* Wq_out  = (const float*)d_in[10];
  const float* bq_out  = (const float*)d_in[11];
  const float* Wkv_out = (const float*)d_in[12];
  const float* bkv_out = (const float*)d_in[13];
  const float* Weg_out = (const float*)d_in[14];
  const float* beg_out = (const float*)d_in[15];
  const float* Wo      = (const float*)d_in[16];
  const float* bo      = (const float*)d_in[17];

  float* ws = (float*)d_ws;
  unsigned short* elnbf = (unsigned short*)(ws + OFF_ELN);
  unsigned short* Ybf   = (unsigned short*)(ws + OFF_YBF);
  float* Yeg            = ws + OFF_YEG;
  unsigned short* WpT   = (unsigned short*)(ws + OFF_WPT);
  float* bp             = ws + OFF_BP;
  unsigned short* WoT   = (unsigned short*)(ws + OFF_WOT);
  float2* bgIn          = (float2*)(ws + OFF_BGI);
  float2* bgOut         = (float2*)(ws + OFF_BGO);
  unsigned short* Vab   = (unsigned short*)(ws + OFF_VAB);
  float* outp = (float*)d_out;

  int pack_total = PC * 256 + PC + 256 * 512;
  hipLaunchKernelGGL(pack_kernel, dim3((pack_total + 255) / 256), dim3(256), 0, stream,
                     Wq_in, bq_in, Wkv_in, bkv_in, Weg_in, beg_in,
                     Wq_out, bq_out, Wkv_out, bkv_out, Weg_out, beg_out, Wo,
                     WpT, bp, WoT);
  hipLaunchKernelGGL(ln_kernel, dim3(NNR / 4), dim3(256), 0, stream, e, ln_g, ln_b, elnbf);
  hipLaunchKernelGGL(proj_kernel, dim3(7, 200), dim3(256), 0, stream, elnbf, WpT, bp, Ybf, Yeg);
  hipLaunchKernelGGL(eg_kernel, dim3((NNR + 255) / 256), dim3(256), 0, stream, Yeg, mask, bgIn, bgOut);
  hipLaunchKernelGGL(attn_kernel, dim3(5, 160, 2), dim3(256), 0, stream, Ybf, bgIn, bgOut, Vab);
  hipLaunchKernelGGL(out_kernel, dim3(2, 400), dim3(256), 0, stream, Vab, WoT, bo, outp);
}

// Round 5
// 236.888 us; speedup vs baseline: 1.8878x; 1.8878x over previous
//
#include <hip/hip_runtime.h>

#define NTOK 160
#define EDIM 256
#define HH 4
#define NNR 25600          // NTOK*NTOK rows
#define PC 784             // packed projection cols
#define YBC 768            // bf16 matmul cols of Y
#define SCALEF 0.125f
#define LNEPS 1e-5f

// ---- workspace layout (float offsets) ----
#define OFF_ELN 0LL                       // bf16 [NNR][256]
#define OFF_YBF (OFF_ELN + 3276800LL)     // bf16 [NNR][768]
#define OFF_WPT (OFF_YBF + 9830400LL)     // bf16 [784][256]
#define OFF_BP  (OFF_WPT + 100352LL)      // fp32 [784]
#define OFF_WOT (OFF_BP  + 800LL)         // bf16 [256][512]
#define OFF_BGI (OFF_WOT + 65536LL)       // half2 [4][NNR]  (bias, gate)
#define OFF_BGO (OFF_BGI + 102400LL)      // half2 [4][NNR]
#define OFF_VAB (OFF_BGO + 102400LL)      // bf16 [NNR][512]
// end = OFF_VAB + 6,553,600 = 20,032,272 floats (~80 MiB)

typedef short bf16x8 __attribute__((ext_vector_type(8)));
typedef unsigned short u16x8 __attribute__((ext_vector_type(8)));
typedef unsigned short u16x4 __attribute__((ext_vector_type(4)));
typedef float f32x4 __attribute__((ext_vector_type(4)));

__device__ __forceinline__ unsigned short bf16_rne(float f) {
  unsigned int u = __float_as_uint(f);
  u += 0x7FFFu + ((u >> 16) & 1u);
  return (unsigned short)(u >> 16);
}
__device__ __forceinline__ unsigned short f2h(float f) {
  _Float16 h = (_Float16)f;
  return *(unsigned short*)&h;
}
__device__ __forceinline__ float h2f(unsigned short u) {
  _Float16 h = *(_Float16*)&u;
  return (float)h;
}

__device__ __forceinline__ float wave_sum(float v) {
  #pragma unroll
  for (int o = 1; o < 64; o <<= 1) v += __shfl_xor(v, o, 64);
  return v;
}

// ---------------- pack: WpT[784][256] bf16, bp[784] f32, WoT[256][512] bf16 ----
// packed col map n: [0,256) Qin(h-major, *SCALE) | [256,320) Kin | [320,384) Vin |
// [384,640) Qout | [640,704) Kout | [704,768) Vout |
// [768,772) E_in | [772,776) G_in | [776,780) E_out | [780,784) G_out
__device__ __forceinline__ void col_map(int n, const float* const* W, const float* const* bia,
                                        const float** Wsel, const float** bsel,
                                        int* col, int* ld, float* scale) {
  *scale = 1.f;
  if (n < 256)      { *Wsel = W[0]; *bsel = bia[0]; *col = (n&63)*4 + (n>>6); *ld = 256; *scale = SCALEF; }
  else if (n < 320) { *Wsel = W[1]; *bsel = bia[1]; *col = n - 256;        *ld = 128; }
  else if (n < 384) { *Wsel = W[1]; *bsel = bia[1]; *col = 64 + n - 320;   *ld = 128; }
  else if (n < 640) { int c2 = n - 384; *Wsel = W[3]; *bsel = bia[3]; *col = (c2&63)*4 + (c2>>6); *ld = 256; *scale = SCALEF; }
  else if (n < 704) { *Wsel = W[4]; *bsel = bia[4]; *col = n - 640;        *ld = 128; }
  else if (n < 768) { *Wsel = W[4]; *bsel = bia[4]; *col = 64 + n - 704;   *ld = 128; }
  else if (n < 772) { *Wsel = W[2]; *bsel = bia[2]; *col = n - 768;        *ld = 8; }
  else if (n < 776) { *Wsel = W[2]; *bsel = bia[2]; *col = 4 + n - 772;    *ld = 8; }
  else if (n < 780) { *Wsel = W[5]; *bsel = bia[5]; *col = n - 776;        *ld = 8; }
  else              { *Wsel = W[5]; *bsel = bia[5]; *col = 4 + n - 780;    *ld = 8; }
}

__global__ void pack_kernel(const float* __restrict__ Wq_in,  const float* __restrict__ bq_in,
                            const float* __restrict__ Wkv_in, const float* __restrict__ bkv_in,
                            const float* __restrict__ Weg_in, const float* __restrict__ beg_in,
                            const float* __restrict__ Wq_out, const float* __restrict__ bq_out,
                            const float* __restrict__ Wkv_out,const float* __restrict__ bkv_out,
                            const float* __restrict__ Weg_out,const float* __restrict__ beg_out,
                            const float* __restrict__ Wo,
                            unsigned short* __restrict__ WpT, float* __restrict__ bp,
                            unsigned short* __restrict__ WoT) {
  const float* W[6]  = {Wq_in, Wkv_in, Weg_in, Wq_out, Wkv_out, Weg_out};
  const float* bi[6] = {bq_in, bkv_in, beg_in, bq_out, bkv_out, beg_out};
  int idx = blockIdx.x * blockDim.x + threadIdx.x;
  if (idx < PC * 256) {
    int n = idx >> 8, k = idx & 255;
    const float *Ws, *bs; int col, ld; float sc;
    col_map(n, W, bi, &Ws, &bs, &col, &ld, &sc);
    WpT[idx] = bf16_rne(Ws[(long long)k * ld + col] * sc);
  } else if (idx < PC * 256 + PC) {
    int n = idx - PC * 256;
    const float *Ws, *bs; int col, ld; float sc;
    col_map(n, W, bi, &Ws, &bs, &col, &ld, &sc);
    bp[n] = bs[col] * sc;
  } else if (idx < PC * 256 + PC + 256 * 512) {
    int q = idx - (PC * 256 + PC);
    int n = q >> 9, kk = q & 511;
    int brn = kk >> 8, hh = (kk >> 6) & 3, dd = kk & 63;
    WoT[q] = bf16_rne(Wo[(long long)(dd * 8 + hh + 4 * brn) * 256 + n]);
  }
}

// ---------------- layernorm -> bf16: one wave per row ----------------
__global__ __launch_bounds__(256) void ln_kernel(const float* __restrict__ e,
                                                 const float* __restrict__ g,
                                                 const float* __restrict__ b,
                                                 unsigned short* __restrict__ elnbf) {
  int row  = blockIdx.x * 4 + (threadIdx.x >> 6);
  int lane = threadIdx.x & 63;
  float4 x = ((const float4*)(e + (long long)row * EDIM))[lane];
  float s = wave_sum(x.x + x.y + x.z + x.w);
  float mu = s * (1.f / EDIM);
  float d0 = x.x - mu, d1 = x.y - mu, d2 = x.z - mu, d3 = x.w - mu;
  float v = wave_sum(d0*d0 + d1*d1 + d2*d2 + d3*d3);
  float rs = rsqrtf(v * (1.f / EDIM) + LNEPS);
  float4 gg = ((const float4*)g)[lane], bb = ((const float4*)b)[lane];
  u16x4 y;
  y[0] = bf16_rne(d0 * rs * gg.x + bb.x);
  y[1] = bf16_rne(d1 * rs * gg.y + bb.y);
  y[2] = bf16_rne(d2 * rs * gg.z + bb.z);
  y[3] = bf16_rne(d3 * rs * gg.w + bb.w);
  *(u16x4*)&elnbf[(long long)row * EDIM + lane * 4] = y;
}

// ---------------- projection GEMM (MFMA): Y = eln @ Wp + bp; E/G fused epilogue ----
// grid (7 x 112 cols, 200 x 128 rows), 256 thr, K-step 64
__global__ __launch_bounds__(256) void proj_kernel(const unsigned short* __restrict__ Abf,
                                                   const unsigned short* __restrict__ WpT,
                                                   const float* __restrict__ bp,
                                                   const float* __restrict__ mask,
                                                   unsigned short* __restrict__ Ybf,
                                                   unsigned short* __restrict__ bgIn,
                                                   unsigned short* __restrict__ bgOut) {
  __shared__ unsigned short As[128][72];
  __shared__ unsigned short Bs[112][72];
  const int n0 = blockIdx.x * 112;
  const int m0 = blockIdx.y * 128;
  const int t = threadIdx.x;
  const int lane = t & 63, w = t >> 6;
  const int quad = lane >> 4, l15 = lane & 15;
  f32x4 acc[2][7];
  #pragma unroll
  for (int a = 0; a < 2; ++a)
    #pragma unroll
    for (int c = 0; c < 7; ++c) acc[a][c] = (f32x4){0.f,0.f,0.f,0.f};
  for (int k0 = 0; k0 < 256; k0 += 64) {
    #pragma unroll
    for (int p = 0; p < 4; ++p) {
      int f = t + p * 256;
      int row = f >> 3, c = (f & 7) << 3;
      *(u16x8*)&As[row][c] = *(const u16x8*)&Abf[(long long)(m0 + row) * 256 + k0 + c];
    }
    #pragma unroll
    for (int p = 0; p < 4; ++p) {
      int f = t + p * 256;
      int row = f >> 3, c = (f & 7) << 3;
      if (row < 112)
        *(u16x8*)&Bs[row][c] = *(const u16x8*)&WpT[(long long)(n0 + row) * 256 + k0 + c];
    }
    __syncthreads();
    #pragma unroll
    for (int ks = 0; ks < 2; ++ks) {
      bf16x8 a0 = *(const bf16x8*)&As[w * 32 + l15][ks * 32 + quad * 8];
      bf16x8 a1 = *(const bf16x8*)&As[w * 32 + 16 + l15][ks * 32 + quad * 8];
      #pragma unroll
      for (int nt = 0; nt < 7; ++nt) {
        bf16x8 bfr = *(const bf16x8*)&Bs[nt * 16 + l15][ks * 32 + quad * 8];
        acc[0][nt] = __builtin_amdgcn_mfma_f32_16x16x32_bf16(a0, bfr, acc[0][nt], 0, 0, 0);
        acc[1][nt] = __builtin_amdgcn_mfma_f32_16x16x32_bf16(a1, bfr, acc[1][nt], 0, 0, 0);
      }
    }
    __syncthreads();
  }
  #pragma unroll
  for (int nt = 0; nt < 7; ++nt) {
    int col = n0 + nt * 16 + l15;
    float bias = bp[col];
    #pragma unroll
    for (int mt = 0; mt < 2; ++mt) {
      #pragma unroll
      for (int r = 0; r < 4; ++r) {
        long long row = m0 + w * 32 + mt * 16 + quad * 4 + r;
        float v = acc[mt][nt][r] + bias;
        if (col < YBC) {
          Ybf[row * YBC + col] = bf16_rne(v);
        } else {
          // E/G epilogue: col-768 -> kind=idx>>2 (0 Ein,1 Gin,2 Eout,3 Gout), h=idx&3
          int idx = col - YBC;
          int kind = idx >> 2, h = idx & 3;
          float m = mask[row];
          float x = v + m;
          if (kind & 1) x = 1.f / (1.f + __expf(-x));   // gate
          long long rr;
          if (kind < 2) rr = row;
          else {
            int i = (int)(row % NTOK), k = (int)(row / NTOK);
            rr = (long long)i * NTOK + k;
          }
          unsigned short* dst = (kind < 2) ? bgIn : bgOut;
          dst[((long long)h * NNR + rr) * 2 + (kind & 1)] = f2h(x);
        }
      }
    }
  }
}

// ---------------- attention: wave = head, one barrier. grid (10, 160, 2) ----------------
__global__ __launch_bounds__(256) void attn_kernel(const unsigned short* __restrict__ Ybf,
                                                   const unsigned int* __restrict__ bgInU,
                                                   const unsigned int* __restrict__ bgOutU,
                                                   unsigned short* __restrict__ Vab) {
  __shared__ unsigned short Kl[160][72];       // [k_token][d]
  __shared__ unsigned short Vt[64][168];       // [d][k_token]
  __shared__ unsigned short Pl[HH][16][168];   // per-head probs (A-layout rows)
  const int i0 = blockIdx.x * 16;
  const int j  = blockIdx.y;
  const int br = blockIdx.z;
  const int t  = threadIdx.x;
  const int kb = br ? 640 : 256, vb = kb + 64, qb = br ? 384 : 0;
  const unsigned int* bg = br ? bgOutU : bgInU;

  for (int f = t; f < 160 * 8; f += 256) {
    int k = f >> 3, c = (f & 7) << 3;
    long long row = br ? ((long long)k * NTOK + j) : ((long long)j * NTOK + k);
    *(u16x8*)&Kl[k][c] = *(const u16x8*)&Ybf[row * YBC + kb + c];
  }
  for (int f = t; f < 160 * 8; f += 256) {
    int k = f >> 3, g = f & 7, c = g << 3;
    long long row = br ? ((long long)k * NTOK + j) : ((long long)j * NTOK + k);
    u16x8 v = *(const u16x8*)&Ybf[row * YBC + vb + c];
    #pragma unroll
    for (int m = 0; m < 8; ++m) { int mm = (m + g) & 7; Vt[c + mm][k] = v[mm]; }
  }
  __syncthreads();

  const int lane = t & 63, h = t >> 6;     // wave w == head h
  const int quad = lane >> 4, l15 = lane & 15;

  // ---- QK^T: S[i=quad*4+r][kt=n*16+l15] in registers ----
  f32x4 acc[10];
  #pragma unroll
  for (int n = 0; n < 10; ++n) acc[n] = (f32x4){0.f,0.f,0.f,0.f};
  const unsigned short* qp = &Ybf[((long long)(i0 + l15) * NTOK + j) * YBC + qb + h * 64 + quad * 8];
  bf16x8 a0 = *(const bf16x8*)qp;
  bf16x8 a1 = *(const bf16x8*)(qp + 32);
  #pragma unroll
  for (int n = 0; n < 10; ++n) {
    acc[n] = __builtin_amdgcn_mfma_f32_16x16x32_bf16(a0, *(const bf16x8*)&Kl[n*16 + l15][quad*8],      acc[n], 0,0,0);
    acc[n] = __builtin_amdgcn_mfma_f32_16x16x32_bf16(a1, *(const bf16x8*)&Kl[n*16 + l15][32 + quad*8], acc[n], 0,0,0);
  }
  // ---- softmax (sum-only: logits O(1); normalization deferred to PV output) ----
  float sum[4] = {0.f, 0.f, 0.f, 0.f};
  const unsigned int* bgh = bg + (long long)h * NNR + (long long)i0 * NTOK;
  #pragma unroll
  for (int n = 0; n < 10; ++n) {
    #pragma unroll
    for (int r = 0; r < 4; ++r) {
      unsigned int u = bgh[(quad * 4 + r) * NTOK + n * 16 + l15];
      float bias = h2f((unsigned short)(u & 0xFFFFu));
      float gate = h2f((unsigned short)(u >> 16));
      float q = __expf(acc[n][r] + bias);
      sum[r] += q;
      Pl[h][quad * 4 + r][n * 16 + l15] = bf16_rne(q * gate);
    }
  }
  #pragma unroll
  for (int r = 0; r < 4; ++r) {
    #pragma unroll
    for (int m = 1; m < 16; m <<= 1) sum[r] += __shfl_xor(sum[r], m, 64);
  }
  // ---- PV (wave-private Pl; no barrier needed) ----
  f32x4 o[4];
  #pragma unroll
  for (int d = 0; d < 4; ++d) o[d] = (f32x4){0.f,0.f,0.f,0.f};
  #pragma unroll
  for (int ks = 0; ks < 5; ++ks) {
    bf16x8 af = *(const bf16x8*)&Pl[h][l15][ks * 32 + quad * 8];
    #pragma unroll
    for (int d = 0; d < 4; ++d)
      o[d] = __builtin_amdgcn_mfma_f32_16x16x32_bf16(af, *(const bf16x8*)&Vt[d*16 + l15][ks*32 + quad*8], o[d], 0,0,0);
  }
  float inv[4];
  #pragma unroll
  for (int r = 0; r < 4; ++r) inv[r] = 1.f / sum[r];
  #pragma unroll
  for (int d = 0; d < 4; ++d)
    #pragma unroll
    for (int r = 0; r < 4; ++r)
      Vab[((long long)(i0 + quad*4 + r) * NTOK + j) * 512 + br*256 + h*64 + d*16 + l15] =
          bf16_rne(o[d][r] * inv[r]);
}

// ---------------- output GEMM (MFMA): out = Va @ WoT^T + bo ----------------
// grid (2 x 128 cols, 400 x 64 rows), 256 thr, K-step 64
__global__ __launch_bounds__(256) void out_kernel(const unsigned short* __restrict__ Vab,
                                                  const unsigned short* __restrict__ WoT,
                                                  const float* __restrict__ bo,
                                                  float* __restrict__ out) {
  __shared__ unsigned short As[64][72];
  __shared__ unsigned short Bs[128][72];
  const int n0 = blockIdx.x * 128;
  const int m0 = blockIdx.y * 64;
  const int t = threadIdx.x;
  const int lane = t & 63, w = t >> 6;
  const int quad = lane >> 4, l15 = lane & 15;
  f32x4 acc[8];
  #pragma unroll
  for (int c = 0; c < 8; ++c) acc[c] = (f32x4){0.f,0.f,0.f,0.f};
  for (int k0 = 0; k0 < 512; k0 += 64) {
    #pragma unroll
    for (int p = 0; p < 2; ++p) {
      int f = t + p * 256;
      int row = f >> 3, c = (f & 7) << 3;
      *(u16x8*)&As[row][c] = *(const u16x8*)&Vab[(long long)(m0 + row) * 512 + k0 + c];
    }
    #pragma unroll
    for (int p = 0; p < 4; ++p) {
      int f = t + p * 256;
      int row = f >> 3, c = (f & 7) << 3;
      *(u16x8*)&Bs[row][c] = *(const u16x8*)&WoT[(long long)(n0 + row) * 512 + k0 + c];
    }
    __syncthreads();
    #pragma unroll
    for (int ks = 0; ks < 2; ++ks) {
      bf16x8 a0 = *(const bf16x8*)&As[w * 16 + l15][ks * 32 + quad * 8];
      #pragma unroll
      for (int nt = 0; nt < 8; ++nt) {
        bf16x8 bfr = *(const bf16x8*)&Bs[nt * 16 + l15][ks * 32 + quad * 8];
        acc[nt] = __builtin_amdgcn_mfma_f32_16x16x32_bf16(a0, bfr, acc[nt], 0, 0, 0);
      }
    }
    __syncthreads();
  }
  #pragma unroll
  for (int nt = 0; nt < 8; ++nt) {
    int col = n0 + nt * 16 + l15;
    float bias = bo[col];
    #pragma unroll
    for (int r = 0; r < 4; ++r) {
      long long row = m0 + w * 16 + quad * 4 + r;
      out[row * 256 + col] = acc[nt][r] + bias;
    }
  }
}

extern "C" void kernel_launch(void* const* d_in, const int* in_sizes, int n_in,
                              void* d_out, int out_size, void* d_ws, size_t ws_size,
                              hipStream_t stream) {
  const float* e       = (const float*)d_in[0];
  const float* mask    = (const float*)d_in[1];
  const float* ln_g    = (const float*)d_in[2];
  const float* ln_b    = (const float*)d_in[3];
  const float* Wq_in   = (const float*)d_in[4];
  const float* bq_in   = (const float*)d_in[5];
  const float* Wkv_in  = (const float*)d_in[6];
  const float* bkv_in  = (const float*)d_in[7];
  const float* Weg_in  = (const float*)d_in[8];
  const float* beg_in  = (const float*)d_in[9];
  const float* Wq_out  = (const float*)d_in[10];
  const float* bq_out  = (const float*)d_in[11];
  const float* Wkv_out = (const float*)d_in[12];
  const float* bkv_out = (const float*)d_in[13];
  const float* Weg_out = (const float*)d_in[14];
  const float* beg_out = (const float*)d_in[15];
  const float* Wo      = (const float*)d_in[16];
  const float* bo      = (const float*)d_in[17];

  float* ws = (float*)d_ws;
  unsigned short* elnbf = (unsigned short*)(ws + OFF_ELN);
  unsigned short* Ybf   = (unsigned short*)(ws + OFF_YBF);
  unsigned short* WpT   = (unsigned short*)(ws + OFF_WPT);
  float* bp             = ws + OFF_BP;
  unsigned short* WoT   = (unsigned short*)(ws + OFF_WOT);
  unsigned short* bgIn  = (unsigned short*)(ws + OFF_BGI);
  unsigned short* bgOut = (unsigned short*)(ws + OFF_BGO);
  unsigned short* Vab   = (unsigned short*)(ws + OFF_VAB);
  float* outp = (float*)d_out;

  int pack_total = PC * 256 + PC + 256 * 512;
  hipLaunchKernelGGL(pack_kernel, dim3((pack_total + 255) / 256), dim3(256), 0, stream,
                     Wq_in, bq_in, Wkv_in, bkv_in, Weg_in, beg_in,
                     Wq_out, bq_out, Wkv_out, bkv_out, Weg_out, beg_out, Wo,
                     WpT, bp, WoT);
  hipLaunchKernelGGL(ln_kernel, dim3(NNR / 4), dim3(256), 0, stream, e, ln_g, ln_b, elnbf);
  hipLaunchKernelGGL(proj_kernel, dim3(7, 200), dim3(256), 0, stream, elnbf, WpT, bp, mask,
                     Ybf, bgIn, bgOut);
  hipLaunchKernelGGL(attn_kernel, dim3(10, 160, 2), dim3(256), 0, stream, Ybf,
                     (const unsigned int*)bgIn, (const unsigned int*)bgOut, Vab);
  hipLaunchKernelGGL(out_kernel, dim3(2, 400), dim3(256), 0, stream, Vab, WoT, bo, outp);
}

// Round 6
// 219.411 us; speedup vs baseline: 2.0382x; 1.0797x over previous
//
#include <hip/hip_runtime.h>

#define NTOK 160
#define EDIM 256
#define HH 4
#define NNR 25600          // NTOK*NTOK rows
#define PC 784             // packed projection cols
#define YBC 768            // bf16 matmul cols of Y
#define SCALEF 0.125f
#define LNEPS 1e-5f

// ---- workspace layout (float offsets) ----
#define OFF_ELN 0LL                       // bf16 [NNR][256]
#define OFF_YBF (OFF_ELN + 3276800LL)     // bf16 [NNR][768]
#define OFF_WPT (OFF_YBF + 9830400LL)     // bf16 [784][256]
#define OFF_BP  (OFF_WPT + 100352LL)      // fp32 [784]
#define OFF_WOT (OFF_BP  + 800LL)         // bf16 [256][512]
#define OFF_BGI (OFF_WOT + 65536LL)       // half2 [4][NNR]  (bias, gate)
#define OFF_BGO (OFF_BGI + 102400LL)      // half2 [4][NNR]
#define OFF_VAB (OFF_BGO + 102400LL)      // bf16 [NNR][512]
// end = OFF_VAB + 6,553,600 = 20,032,272 floats (~80 MiB)

#define LN_BLOCKS 6400
#define PACK_TOTAL (PC * 256 + PC + 256 * 512)   // 331,792
#define PACK_BLOCKS ((PACK_TOTAL + 255) / 256)   // 1297

typedef short bf16x8 __attribute__((ext_vector_type(8)));
typedef unsigned short u16x8 __attribute__((ext_vector_type(8)));
typedef unsigned short u16x4 __attribute__((ext_vector_type(4)));
typedef float f32x4 __attribute__((ext_vector_type(4)));

__device__ __forceinline__ unsigned short bf16_rne(float f) {
  unsigned int u = __float_as_uint(f);
  u += 0x7FFFu + ((u >> 16) & 1u);
  return (unsigned short)(u >> 16);
}
__device__ __forceinline__ unsigned short f2h(float f) {
  _Float16 h = (_Float16)f;
  return *(unsigned short*)&h;
}
__device__ __forceinline__ float h2f(unsigned short u) {
  _Float16 h = *(_Float16*)&u;
  return (float)h;
}

__device__ __forceinline__ float wave_sum(float v) {
  #pragma unroll
  for (int o = 1; o < 64; o <<= 1) v += __shfl_xor(v, o, 64);
  return v;
}

// packed col map n: [0,256) Qin(h-major, *SCALE) | [256,320) Kin | [320,384) Vin |
// [384,640) Qout | [640,704) Kout | [704,768) Vout |
// [768,772) E_in | [772,776) G_in | [776,780) E_out | [780,784) G_out
__device__ __forceinline__ void col_map(int n, const float* const* W, const float* const* bia,
                                        const float** Wsel, const float** bsel,
                                        int* col, int* ld, float* scale) {
  *scale = 1.f;
  if (n < 256)      { *Wsel = W[0]; *bsel = bia[0]; *col = (n&63)*4 + (n>>6); *ld = 256; *scale = SCALEF; }
  else if (n < 320) { *Wsel = W[1]; *bsel = bia[1]; *col = n - 256;        *ld = 128; }
  else if (n < 384) { *Wsel = W[1]; *bsel = bia[1]; *col = 64 + n - 320;   *ld = 128; }
  else if (n < 640) { int c2 = n - 384; *Wsel = W[3]; *bsel = bia[3]; *col = (c2&63)*4 + (c2>>6); *ld = 256; *scale = SCALEF; }
  else if (n < 704) { *Wsel = W[4]; *bsel = bia[4]; *col = n - 640;        *ld = 128; }
  else if (n < 768) { *Wsel = W[4]; *bsel = bia[4]; *col = 64 + n - 704;   *ld = 128; }
  else if (n < 772) { *Wsel = W[2]; *bsel = bia[2]; *col = n - 768;        *ld = 8; }
  else if (n < 776) { *Wsel = W[2]; *bsel = bia[2]; *col = 4 + n - 772;    *ld = 8; }
  else if (n < 780) { *Wsel = W[5]; *bsel = bia[5]; *col = n - 776;        *ld = 8; }
  else              { *Wsel = W[5]; *bsel = bia[5]; *col = 4 + n - 780;    *ld = 8; }
}

// ---------------- prep: layernorm->bf16 (blocks [0,6400)) + weight pack (rest) ----------------
__global__ __launch_bounds__(256) void prep_kernel(const float* __restrict__ e,
                                                   const float* __restrict__ g,
                                                   const float* __restrict__ b,
                                                   unsigned short* __restrict__ elnbf,
                                                   const float* __restrict__ Wq_in,  const float* __restrict__ bq_in,
                                                   const float* __restrict__ Wkv_in, const float* __restrict__ bkv_in,
                                                   const float* __restrict__ Weg_in, const float* __restrict__ beg_in,
                                                   const float* __restrict__ Wq_out, const float* __restrict__ bq_out,
                                                   const float* __restrict__ Wkv_out,const float* __restrict__ bkv_out,
                                                   const float* __restrict__ Weg_out,const float* __restrict__ beg_out,
                                                   const float* __restrict__ Wo,
                                                   unsigned short* __restrict__ WpT, float* __restrict__ bp,
                                                   unsigned short* __restrict__ WoT) {
  if (blockIdx.x < LN_BLOCKS) {
    int row  = blockIdx.x * 4 + (threadIdx.x >> 6);
    int lane = threadIdx.x & 63;
    float4 x = ((const float4*)(e + (long long)row * EDIM))[lane];
    float s = wave_sum(x.x + x.y + x.z + x.w);
    float mu = s * (1.f / EDIM);
    float d0 = x.x - mu, d1 = x.y - mu, d2 = x.z - mu, d3 = x.w - mu;
    float v = wave_sum(d0*d0 + d1*d1 + d2*d2 + d3*d3);
    float rs = rsqrtf(v * (1.f / EDIM) + LNEPS);
    float4 gg = ((const float4*)g)[lane], bb = ((const float4*)b)[lane];
    u16x4 y;
    y[0] = bf16_rne(d0 * rs * gg.x + bb.x);
    y[1] = bf16_rne(d1 * rs * gg.y + bb.y);
    y[2] = bf16_rne(d2 * rs * gg.z + bb.z);
    y[3] = bf16_rne(d3 * rs * gg.w + bb.w);
    *(u16x4*)&elnbf[(long long)row * EDIM + lane * 4] = y;
    return;
  }
  const float* W[6]  = {Wq_in, Wkv_in, Weg_in, Wq_out, Wkv_out, Weg_out};
  const float* bi[6] = {bq_in, bkv_in, beg_in, bq_out, bkv_out, beg_out};
  int idx = (blockIdx.x - LN_BLOCKS) * blockDim.x + threadIdx.x;
  if (idx < PC * 256) {
    int n = idx >> 8, k = idx & 255;
    const float *Ws, *bs; int col, ld; float sc;
    col_map(n, W, bi, &Ws, &bs, &col, &ld, &sc);
    WpT[idx] = bf16_rne(Ws[(long long)k * ld + col] * sc);
  } else if (idx < PC * 256 + PC) {
    int n = idx - PC * 256;
    const float *Ws, *bs; int col, ld; float sc;
    col_map(n, W, bi, &Ws, &bs, &col, &ld, &sc);
    bp[n] = bs[col] * sc;
  } else if (idx < PC * 256 + PC + 256 * 512) {
    int q = idx - (PC * 256 + PC);
    int n = q >> 9, kk = q & 511;
    int brn = kk >> 8, hh = (kk >> 6) & 3, dd = kk & 63;
    WoT[q] = bf16_rne(Wo[(long long)(dd * 8 + hh + 4 * brn) * 256 + n]);
  }
}

// ---------------- projection GEMM (MFMA): Y = eln @ Wp + bp; E/G fused epilogue ----
// grid (7 x 112 cols, 200 x 128 rows), 256 thr, K-step 64
__global__ __launch_bounds__(256) void proj_kernel(const unsigned short* __restrict__ Abf,
                                                   const unsigned short* __restrict__ WpT,
                                                   const float* __restrict__ bp,
                                                   const float* __restrict__ mask,
                                                   unsigned short* __restrict__ Ybf,
                                                   unsigned short* __restrict__ bgIn,
                                                   unsigned short* __restrict__ bgOut) {
  __shared__ unsigned short As[128][72];
  __shared__ unsigned short Bs[112][72];
  const int n0 = blockIdx.x * 112;
  const int m0 = blockIdx.y * 128;
  const int t = threadIdx.x;
  const int lane = t & 63, w = t >> 6;
  const int quad = lane >> 4, l15 = lane & 15;
  f32x4 acc[2][7];
  #pragma unroll
  for (int a = 0; a < 2; ++a)
    #pragma unroll
    for (int c = 0; c < 7; ++c) acc[a][c] = (f32x4){0.f,0.f,0.f,0.f};
  for (int k0 = 0; k0 < 256; k0 += 64) {
    #pragma unroll
    for (int p = 0; p < 4; ++p) {
      int f = t + p * 256;
      int row = f >> 3, c = (f & 7) << 3;
      *(u16x8*)&As[row][c] = *(const u16x8*)&Abf[(long long)(m0 + row) * 256 + k0 + c];
    }
    #pragma unroll
    for (int p = 0; p < 4; ++p) {
      int f = t + p * 256;
      int row = f >> 3, c = (f & 7) << 3;
      if (row < 112)
        *(u16x8*)&Bs[row][c] = *(const u16x8*)&WpT[(long long)(n0 + row) * 256 + k0 + c];
    }
    __syncthreads();
    #pragma unroll
    for (int ks = 0; ks < 2; ++ks) {
      bf16x8 a0 = *(const bf16x8*)&As[w * 32 + l15][ks * 32 + quad * 8];
      bf16x8 a1 = *(const bf16x8*)&As[w * 32 + 16 + l15][ks * 32 + quad * 8];
      #pragma unroll
      for (int nt = 0; nt < 7; ++nt) {
        bf16x8 bfr = *(const bf16x8*)&Bs[nt * 16 + l15][ks * 32 + quad * 8];
        acc[0][nt] = __builtin_amdgcn_mfma_f32_16x16x32_bf16(a0, bfr, acc[0][nt], 0, 0, 0);
        acc[1][nt] = __builtin_amdgcn_mfma_f32_16x16x32_bf16(a1, bfr, acc[1][nt], 0, 0, 0);
      }
    }
    __syncthreads();
  }
  #pragma unroll
  for (int nt = 0; nt < 7; ++nt) {
    int col = n0 + nt * 16 + l15;
    float bias = bp[col];
    #pragma unroll
    for (int mt = 0; mt < 2; ++mt) {
      #pragma unroll
      for (int r = 0; r < 4; ++r) {
        long long row = m0 + w * 32 + mt * 16 + quad * 4 + r;
        float v = acc[mt][nt][r] + bias;
        if (col < YBC) {
          Ybf[row * YBC + col] = bf16_rne(v);
        } else {
          // E/G epilogue: col-768 -> kind=idx>>2 (0 Ein,1 Gin,2 Eout,3 Gout), h=idx&3
          int idx = col - YBC;
          int kind = idx >> 2, h = idx & 3;
          float m = mask[row];
          float x = v + m;
          if (kind & 1) x = 1.f / (1.f + __expf(-x));   // gate
          long long rr;
          if (kind < 2) rr = row;
          else {
            int i = (int)(row % NTOK), k = (int)(row / NTOK);
            rr = (long long)i * NTOK + k;
          }
          unsigned short* dst = (kind < 2) ? bgIn : bgOut;
          dst[((long long)h * NNR + rr) * 2 + (kind & 1)] = f2h(x);
        }
      }
    }
  }
}

// ---------------- attention: wave = head; Pl aliases Kl (dead after QK). grid (10,160,2) ----
// LDS = Kl(160*72) ∪ Pl(64*168)  +  Vt(64*168)  = 44,544 B  -> 3 blocks/CU
__global__ __launch_bounds__(256) void attn_kernel(const unsigned short* __restrict__ Ybf,
                                                   const unsigned int* __restrict__ bgInU,
                                                   const unsigned int* __restrict__ bgOutU,
                                                   unsigned short* __restrict__ Vab) {
  __shared__ unsigned short smem[11520 + 10752];
  unsigned short (* __restrict__ Kl)[72]  = (unsigned short(*)[72])smem;            // [160][72]
  unsigned short (* __restrict__ Vt)[168] = (unsigned short(*)[168])(smem + 11520); // [64][168]
  unsigned short (* __restrict__ Pl)[168] = (unsigned short(*)[168])smem;           // [64][168] row=h*16+i
  const int i0 = blockIdx.x * 16;
  const int j  = blockIdx.y;
  const int br = blockIdx.z;
  const int t  = threadIdx.x;
  const int kb = br ? 640 : 256, vb = kb + 64, qb = br ? 384 : 0;
  const unsigned int* bg = br ? bgOutU : bgInU;

  for (int f = t; f < 160 * 8; f += 256) {
    int k = f >> 3, c = (f & 7) << 3;
    long long row = br ? ((long long)k * NTOK + j) : ((long long)j * NTOK + k);
    *(u16x8*)&Kl[k][c] = *(const u16x8*)&Ybf[row * YBC + kb + c];
  }
  for (int f = t; f < 160 * 8; f += 256) {
    int k = f >> 3, g = f & 7, c = g << 3;
    long long row = br ? ((long long)k * NTOK + j) : ((long long)j * NTOK + k);
    u16x8 v = *(const u16x8*)&Ybf[row * YBC + vb + c];
    #pragma unroll
    for (int m = 0; m < 8; ++m) { int mm = (m + g) & 7; Vt[c + mm][k] = v[mm]; }
  }
  __syncthreads();

  const int lane = t & 63, h = t >> 6;     // wave w == head h
  const int quad = lane >> 4, l15 = lane & 15;

  // ---- QK^T: S[i=quad*4+r][kt=n*16+l15] in registers ----
  f32x4 acc[10];
  #pragma unroll
  for (int n = 0; n < 10; ++n) acc[n] = (f32x4){0.f,0.f,0.f,0.f};
  const unsigned short* qp = &Ybf[((long long)(i0 + l15) * NTOK + j) * YBC + qb + h * 64 + quad * 8];
  bf16x8 a0 = *(const bf16x8*)qp;
  bf16x8 a1 = *(const bf16x8*)(qp + 32);
  #pragma unroll
  for (int n = 0; n < 10; ++n) {
    acc[n] = __builtin_amdgcn_mfma_f32_16x16x32_bf16(a0, *(const bf16x8*)&Kl[n*16 + l15][quad*8],      acc[n], 0,0,0);
    acc[n] = __builtin_amdgcn_mfma_f32_16x16x32_bf16(a1, *(const bf16x8*)&Kl[n*16 + l15][32 + quad*8], acc[n], 0,0,0);
  }
  __syncthreads();   // Kl dead; its space becomes Pl

  // ---- softmax (sum-only: logits O(1); normalization deferred to PV output) ----
  float sum[4] = {0.f, 0.f, 0.f, 0.f};
  const unsigned int* bgh = bg + (long long)h * NNR + (long long)i0 * NTOK;
  #pragma unroll
  for (int n = 0; n < 10; ++n) {
    #pragma unroll
    for (int r = 0; r < 4; ++r) {
      unsigned int u = bgh[(quad * 4 + r) * NTOK + n * 16 + l15];
      float bias = h2f((unsigned short)(u & 0xFFFFu));
      float gate = h2f((unsigned short)(u >> 16));
      float q = __expf(acc[n][r] + bias);
      sum[r] += q;
      Pl[h * 16 + quad * 4 + r][n * 16 + l15] = bf16_rne(q * gate);
    }
  }
  #pragma unroll
  for (int r = 0; r < 4; ++r) {
    #pragma unroll
    for (int m = 1; m < 16; m <<= 1) sum[r] += __shfl_xor(sum[r], m, 64);
  }
  // ---- PV (wave-private Pl rows; no barrier needed) ----
  f32x4 o[4];
  #pragma unroll
  for (int d = 0; d < 4; ++d) o[d] = (f32x4){0.f,0.f,0.f,0.f};
  #pragma unroll
  for (int ks = 0; ks < 5; ++ks) {
    bf16x8 af = *(const bf16x8*)&Pl[h * 16 + l15][ks * 32 + quad * 8];
    #pragma unroll
    for (int d = 0; d < 4; ++d)
      o[d] = __builtin_amdgcn_mfma_f32_16x16x32_bf16(af, *(const bf16x8*)&Vt[d*16 + l15][ks*32 + quad*8], o[d], 0,0,0);
  }
  float inv[4];
  #pragma unroll
  for (int r = 0; r < 4; ++r) inv[r] = 1.f / sum[r];
  #pragma unroll
  for (int d = 0; d < 4; ++d)
    #pragma unroll
    for (int r = 0; r < 4; ++r)
      Vab[((long long)(i0 + quad*4 + r) * NTOK + j) * 512 + br*256 + h*64 + d*16 + l15] =
          bf16_rne(o[d][r] * inv[r]);
}

// ---------------- output GEMM (MFMA): out = Va @ WoT^T + bo ----------------
// grid (2 x 128 cols, 400 x 64 rows), 256 thr, K-step 64
__global__ __launch_bounds__(256) void out_kernel(const unsigned short* __restrict__ Vab,
                                                  const unsigned short* __restrict__ WoT,
                                                  const float* __restrict__ bo,
                                                  float* __restrict__ out) {
  __shared__ unsigned short As[64][72];
  __shared__ unsigned short Bs[128][72];
  const int n0 = blockIdx.x * 128;
  const int m0 = blockIdx.y * 64;
  const int t = threadIdx.x;
  const int lane = t & 63, w = t >> 6;
  const int quad = lane >> 4, l15 = lane & 15;
  f32x4 acc[8];
  #pragma unroll
  for (int c = 0; c < 8; ++c) acc[c] = (f32x4){0.f,0.f,0.f,0.f};
  for (int k0 = 0; k0 < 512; k0 += 64) {
    #pragma unroll
    for (int p = 0; p < 2; ++p) {
      int f = t + p * 256;
      int row = f >> 3, c = (f & 7) << 3;
      *(u16x8*)&As[row][c] = *(const u16x8*)&Vab[(long long)(m0 + row) * 512 + k0 + c];
    }
    #pragma unroll
    for (int p = 0; p < 4; ++p) {
      int f = t + p * 256;
      int row = f >> 3, c = (f & 7) << 3;
      *(u16x8*)&Bs[row][c] = *(const u16x8*)&WoT[(long long)(n0 + row) * 512 + k0 + c];
    }
    __syncthreads();
    #pragma unroll
    for (int ks = 0; ks < 2; ++ks) {
      bf16x8 a0 = *(const bf16x8*)&As[w * 16 + l15][ks * 32 + quad * 8];
      #pragma unroll
      for (int nt = 0; nt < 8; ++nt) {
        bf16x8 bfr = *(const bf16x8*)&Bs[nt * 16 + l15][ks * 32 + quad * 8];
        acc[nt] = __builtin_amdgcn_mfma_f32_16x16x32_bf16(a0, bfr, acc[nt], 0, 0, 0);
      }
    }
    __syncthreads();
  }
  #pragma unroll
  for (int nt = 0; nt < 8; ++nt) {
    int col = n0 + nt * 16 + l15;
    float bias = bo[col];
    #pragma unroll
    for (int r = 0; r < 4; ++r) {
      long long row = m0 + w * 16 + quad * 4 + r;
      out[row * 256 + col] = acc[nt][r] + bias;
    }
  }
}

extern "C" void kernel_launch(void* const* d_in, const int* in_sizes, int n_in,
                              void* d_out, int out_size, void* d_ws, size_t ws_size,
                              hipStream_t stream) {
  const float* e       = (const float*)d_in[0];
  const float* mask    = (const float*)d_in[1];
  const float* ln_g    = (const float*)d_in[2];
  const float* ln_b    = (const float*)d_in[3];
  const float* Wq_in   = (const float*)d_in[4];
  const float* bq_in   = (const float*)d_in[5];
  const float* Wkv_in  = (const float*)d_in[6];
  const float* bkv_in  = (const float*)d_in[7];
  const float* Weg_in  = (const float*)d_in[8];
  const float* beg_in  = (const float*)d_in[9];
  const float* Wq_out  = (const float*)d_in[10];
  const float* bq_out  = (const float*)d_in[11];
  const float* Wkv_out = (const float*)d_in[12];
  const float* bkv_out = (const float*)d_in[13];
  const float* Weg_out = (const float*)d_in[14];
  const float* beg_out = (const float*)d_in[15];
  const float* Wo      = (const float*)d_in[16];
  const float* bo      = (const float*)d_in[17];

  float* ws = (float*)d_ws;
  unsigned short* elnbf = (unsigned short*)(ws + OFF_ELN);
  unsigned short* Ybf   = (unsigned short*)(ws + OFF_YBF);
  unsigned short* WpT   = (unsigned short*)(ws + OFF_WPT);
  float* bp             = ws + OFF_BP;
  unsigned short* WoT   = (unsigned short*)(ws + OFF_WOT);
  unsigned short* bgIn  = (unsigned short*)(ws + OFF_BGI);
  unsigned short* bgOut = (unsigned short*)(ws + OFF_BGO);
  unsigned short* Vab   = (unsigned short*)(ws + OFF_VAB);
  float* outp = (float*)d_out;

  hipLaunchKernelGGL(prep_kernel, dim3(LN_BLOCKS + PACK_BLOCKS), dim3(256), 0, stream,
                     e, ln_g, ln_b, elnbf,
                     Wq_in, bq_in, Wkv_in, bkv_in, Weg_in, beg_in,
                     Wq_out, bq_out, Wkv_out, bkv_out, Weg_out, beg_out, Wo,
                     WpT, bp, WoT);
  hipLaunchKernelGGL(proj_kernel, dim3(7, 200), dim3(256), 0, stream, elnbf, WpT, bp, mask,
                     Ybf, bgIn, bgOut);
  hipLaunchKernelGGL(attn_kernel, dim3(10, 160, 2), dim3(256), 0, stream, Ybf,
                     (const unsigned int*)bgIn, (const unsigned int*)bgOut, Vab);
  hipLaunchKernelGGL(out_kernel, dim3(2, 400), dim3(256), 0, stream, Vab, WoT, bo, outp);
}

// Round 7
// 203.769 us; speedup vs baseline: 2.1947x; 1.0768x over previous
//
#include <hip/hip_runtime.h>

#define NTOK 160
#define EDIM 256
#define HH 4
#define NNR 25600          // NTOK*NTOK rows
#define PC 784             // packed projection cols
#define YBC 768            // bf16 matmul cols of Y
#define SCALEF 0.125f
#define LOG2E 1.44269504f
#define LNEPS 1e-5f

// ---- workspace layout (float offsets) ----
#define OFF_ELN 0LL                       // bf16 [NNR][256]
#define OFF_YBF (OFF_ELN + 3276800LL)     // bf16 [NNR][768]
#define OFF_WPT (OFF_YBF + 9830400LL)     // bf16 [784][256]
#define OFF_BP  (OFF_WPT + 100352LL)      // fp32 [784]
#define OFF_WOT (OFF_BP  + 800LL)         // bf16 [256][512]
#define OFF_BGI (OFF_WOT + 65536LL)       // half2 [4][NNR]  (bias*log2e, gate)
#define OFF_BGO (OFF_BGI + 102400LL)      // half2 [4][NNR]
#define OFF_VAB (OFF_BGO + 102400LL)      // bf16 [NNR][512]
// end = OFF_VAB + 6,553,600 = 20,032,272 floats (~80 MiB)

#define LN_BLOCKS 6400
#define PACK_TOTAL (PC * 256 + PC + 256 * 512)   // 331,792
#define PACK_BLOCKS ((PACK_TOTAL + 255) / 256)   // 1297

typedef short bf16x8 __attribute__((ext_vector_type(8)));
typedef unsigned short u16x8 __attribute__((ext_vector_type(8)));
typedef unsigned short u16x4 __attribute__((ext_vector_type(4)));
typedef float f32x4 __attribute__((ext_vector_type(4)));

__device__ __forceinline__ unsigned short bf16_rne(float f) {
  unsigned int u = __float_as_uint(f);
  u += 0x7FFFu + ((u >> 16) & 1u);
  return (unsigned short)(u >> 16);
}
__device__ __forceinline__ unsigned short f2h(float f) {
  _Float16 h = (_Float16)f;
  return *(unsigned short*)&h;
}
__device__ __forceinline__ float h2f(unsigned short u) {
  _Float16 h = *(_Float16*)&u;
  return (float)h;
}

__device__ __forceinline__ float wave_sum(float v) {
  #pragma unroll
  for (int o = 1; o < 64; o <<= 1) v += __shfl_xor(v, o, 64);
  return v;
}

// packed col map n: [0,256) Qin(h-major, *SCALE*log2e) | [256,320) Kin | [320,384) Vin |
// [384,640) Qout | [640,704) Kout | [704,768) Vout |
// [768,772) E_in | [772,776) G_in | [776,780) E_out | [780,784) G_out
__device__ __forceinline__ void col_map(int n, const float* const* W, const float* const* bia,
                                        const float** Wsel, const float** bsel,
                                        int* col, int* ld, float* scale) {
  *scale = 1.f;
  if (n < 256)      { *Wsel = W[0]; *bsel = bia[0]; *col = (n&63)*4 + (n>>6); *ld = 256; *scale = SCALEF * LOG2E; }
  else if (n < 320) { *Wsel = W[1]; *bsel = bia[1]; *col = n - 256;        *ld = 128; }
  else if (n < 384) { *Wsel = W[1]; *bsel = bia[1]; *col = 64 + n - 320;   *ld = 128; }
  else if (n < 640) { int c2 = n - 384; *Wsel = W[3]; *bsel = bia[3]; *col = (c2&63)*4 + (c2>>6); *ld = 256; *scale = SCALEF * LOG2E; }
  else if (n < 704) { *Wsel = W[4]; *bsel = bia[4]; *col = n - 640;        *ld = 128; }
  else if (n < 768) { *Wsel = W[4]; *bsel = bia[4]; *col = 64 + n - 704;   *ld = 128; }
  else if (n < 772) { *Wsel = W[2]; *bsel = bia[2]; *col = n - 768;        *ld = 8; }
  else if (n < 776) { *Wsel = W[2]; *bsel = bia[2]; *col = 4 + n - 772;    *ld = 8; }
  else if (n < 780) { *Wsel = W[5]; *bsel = bia[5]; *col = n - 776;        *ld = 8; }
  else              { *Wsel = W[5]; *bsel = bia[5]; *col = 4 + n - 780;    *ld = 8; }
}

// ---------------- prep: layernorm->bf16 (blocks [0,6400)) + weight pack (rest) ----------------
__global__ __launch_bounds__(256) void prep_kernel(const float* __restrict__ e,
                                                   const float* __restrict__ g,
                                                   const float* __restrict__ b,
                                                   unsigned short* __restrict__ elnbf,
                                                   const float* __restrict__ Wq_in,  const float* __restrict__ bq_in,
                                                   const float* __restrict__ Wkv_in, const float* __restrict__ bkv_in,
                                                   const float* __restrict__ Weg_in, const float* __restrict__ beg_in,
                                                   const float* __restrict__ Wq_out, const float* __restrict__ bq_out,
                                                   const float* __restrict__ Wkv_out,const float* __restrict__ bkv_out,
                                                   const float* __restrict__ Weg_out,const float* __restrict__ beg_out,
                                                   const float* __restrict__ Wo,
                                                   unsigned short* __restrict__ WpT, float* __restrict__ bp,
                                                   unsigned short* __restrict__ WoT) {
  if (blockIdx.x < LN_BLOCKS) {
    int row  = blockIdx.x * 4 + (threadIdx.x >> 6);
    int lane = threadIdx.x & 63;
    float4 x = ((const float4*)(e + (long long)row * EDIM))[lane];
    float s = wave_sum(x.x + x.y + x.z + x.w);
    float mu = s * (1.f / EDIM);
    float d0 = x.x - mu, d1 = x.y - mu, d2 = x.z - mu, d3 = x.w - mu;
    float v = wave_sum(d0*d0 + d1*d1 + d2*d2 + d3*d3);
    float rs = rsqrtf(v * (1.f / EDIM) + LNEPS);
    float4 gg = ((const float4*)g)[lane], bb = ((const float4*)b)[lane];
    u16x4 y;
    y[0] = bf16_rne(d0 * rs * gg.x + bb.x);
    y[1] = bf16_rne(d1 * rs * gg.y + bb.y);
    y[2] = bf16_rne(d2 * rs * gg.z + bb.z);
    y[3] = bf16_rne(d3 * rs * gg.w + bb.w);
    *(u16x4*)&elnbf[(long long)row * EDIM + lane * 4] = y;
    return;
  }
  const float* W[6]  = {Wq_in, Wkv_in, Weg_in, Wq_out, Wkv_out, Weg_out};
  const float* bi[6] = {bq_in, bkv_in, beg_in, bq_out, bkv_out, beg_out};
  int idx = (blockIdx.x - LN_BLOCKS) * blockDim.x + threadIdx.x;
  if (idx < PC * 256) {
    int n = idx >> 8, k = idx & 255;
    const float *Ws, *bs; int col, ld; float sc;
    col_map(n, W, bi, &Ws, &bs, &col, &ld, &sc);
    WpT[idx] = bf16_rne(Ws[(long long)k * ld + col] * sc);
  } else if (idx < PC * 256 + PC) {
    int n = idx - PC * 256;
    const float *Ws, *bs; int col, ld; float sc;
    col_map(n, W, bi, &Ws, &bs, &col, &ld, &sc);
    bp[n] = bs[col] * sc;
  } else if (idx < PC * 256 + PC + 256 * 512) {
    int q = idx - (PC * 256 + PC);
    int n = q >> 9, kk = q & 511;
    int brn = kk >> 8, hh = (kk >> 6) & 3, dd = kk & 63;
    WoT[q] = bf16_rne(Wo[(long long)(dd * 8 + hh + 4 * brn) * 256 + n]);
  }
}

// ---------------- projection GEMM (MFMA): Y = eln @ Wp + bp; E/G fused epilogue ----
// 1D grid 1400: m = d%200 (A-panel sharers spaced 200 -> same XCD), n = d/200
__global__ __launch_bounds__(256) void proj_kernel(const unsigned short* __restrict__ Abf,
                                                   const unsigned short* __restrict__ WpT,
                                                   const float* __restrict__ bp,
                                                   const float* __restrict__ mask,
                                                   unsigned short* __restrict__ Ybf,
                                                   unsigned short* __restrict__ bgIn,
                                                   unsigned short* __restrict__ bgOut) {
  __shared__ unsigned short As[128][72];
  __shared__ unsigned short Bs[112][72];
  const int d = blockIdx.x;
  const int n0 = (d / 200) * 112;
  const int m0 = (d % 200) * 128;
  const int t = threadIdx.x;
  const int lane = t & 63, w = t >> 6;
  const int quad = lane >> 4, l15 = lane & 15;
  f32x4 acc[2][7];
  #pragma unroll
  for (int a = 0; a < 2; ++a)
    #pragma unroll
    for (int c = 0; c < 7; ++c) acc[a][c] = (f32x4){0.f,0.f,0.f,0.f};
  for (int k0 = 0; k0 < 256; k0 += 64) {
    #pragma unroll
    for (int p = 0; p < 4; ++p) {
      int f = t + p * 256;
      int row = f >> 3, c = (f & 7) << 3;
      *(u16x8*)&As[row][c] = *(const u16x8*)&Abf[(long long)(m0 + row) * 256 + k0 + c];
    }
    #pragma unroll
    for (int p = 0; p < 4; ++p) {
      int f = t + p * 256;
      int row = f >> 3, c = (f & 7) << 3;
      if (row < 112)
        *(u16x8*)&Bs[row][c] = *(const u16x8*)&WpT[(long long)(n0 + row) * 256 + k0 + c];
    }
    __syncthreads();
    #pragma unroll
    for (int ks = 0; ks < 2; ++ks) {
      bf16x8 a0 = *(const bf16x8*)&As[w * 32 + l15][ks * 32 + quad * 8];
      bf16x8 a1 = *(const bf16x8*)&As[w * 32 + 16 + l15][ks * 32 + quad * 8];
      #pragma unroll
      for (int nt = 0; nt < 7; ++nt) {
        bf16x8 bfr = *(const bf16x8*)&Bs[nt * 16 + l15][ks * 32 + quad * 8];
        acc[0][nt] = __builtin_amdgcn_mfma_f32_16x16x32_bf16(a0, bfr, acc[0][nt], 0, 0, 0);
        acc[1][nt] = __builtin_amdgcn_mfma_f32_16x16x32_bf16(a1, bfr, acc[1][nt], 0, 0, 0);
      }
    }
    __syncthreads();
  }
  #pragma unroll
  for (int nt = 0; nt < 7; ++nt) {
    int col = n0 + nt * 16 + l15;
    float bias = bp[col];
    #pragma unroll
    for (int mt = 0; mt < 2; ++mt) {
      #pragma unroll
      for (int r = 0; r < 4; ++r) {
        long long row = m0 + w * 32 + mt * 16 + quad * 4 + r;
        float v = acc[mt][nt][r] + bias;
        if (col < YBC) {
          Ybf[row * YBC + col] = bf16_rne(v);
        } else {
          // E/G epilogue: col-768 -> kind=idx>>2 (0 Ein,1 Gin,2 Eout,3 Gout), h=idx&3
          int idx = col - YBC;
          int kind = idx >> 2, h = idx & 3;
          float m = mask[row];
          float x = v + m;
          if (kind & 1) x = 1.f / (1.f + __expf(-x));   // gate
          else          x = x * LOG2E;                  // bias pre-scaled for exp2
          long long rr;
          if (kind < 2) rr = row;
          else {
            int i = (int)(row % NTOK), k = (int)(row / NTOK);
            rr = (long long)i * NTOK + k;
          }
          unsigned short* dst = (kind < 2) ? bgIn : bgOut;
          dst[((long long)h * NNR + rr) * 2 + (kind & 1)] = f2h(x);
        }
      }
    }
  }
}

// ---------------- attention: 512 thr / 8 waves, wave = (itile,head); Pl aliases Kl ----
// 1D grid 1600: itile = d/320 (K/V sharers spaced 320 -> same XCD), jbr = d%320
// LDS: Pl[128][168] (first 23,040 B doubles as Kl[160][72]) + Vt[64][168] = 64,512 B -> 2 blocks/CU
__global__ __launch_bounds__(512) void attn_kernel(const unsigned short* __restrict__ Ybf,
                                                   const unsigned int* __restrict__ bgInU,
                                                   const unsigned int* __restrict__ bgOutU,
                                                   unsigned short* __restrict__ Vab) {
  __shared__ unsigned short smem[21504 + 10752];
  unsigned short (* __restrict__ Kl)[72]  = (unsigned short(*)[72])smem;            // [160][72]
  unsigned short (* __restrict__ Pl)[168] = (unsigned short(*)[168])smem;           // [128][168]
  unsigned short (* __restrict__ Vt)[168] = (unsigned short(*)[168])(smem + 21504); // [64][168]
  const int d  = blockIdx.x;
  const int jbr = d % 320;
  const int j  = jbr % 160;
  const int br = jbr / 160;
  const int t  = threadIdx.x;
  const int i0 = (d / 320) * 32 + (t >> 8) * 16;   // per-wave i-tile
  const int kb = br ? 640 : 256, vb = kb + 64, qb = br ? 384 : 0;
  const unsigned int* bg = br ? bgOutU : bgInU;

  const int lane = t & 63, h = (t >> 6) & 3;       // wave = (itile, head)
  const int quad = lane >> 4, l15 = lane & 15;
  const int wv = t >> 6;                           // 0..7, Pl row block

  // ---- Q prefetch (before staging barrier) ----
  const unsigned short* qp = &Ybf[((long long)(i0 + l15) * NTOK + j) * YBC + qb + h * 64 + quad * 8];
  bf16x8 a0 = *(const bf16x8*)qp;
  bf16x8 a1 = *(const bf16x8*)(qp + 32);

  // ---- stage K [160][64] ----
  for (int f = t; f < 160 * 8; f += 512) {
    int k = f >> 3, c = (f & 7) << 3;
    long long row = br ? ((long long)k * NTOK + j) : ((long long)j * NTOK + k);
    *(u16x8*)&Kl[k][c] = *(const u16x8*)&Ybf[row * YBC + kb + c];
  }
  // ---- stage V transposed [d][k] (rotated scalar writes) ----
  for (int f = t; f < 160 * 8; f += 512) {
    int k = f >> 3, g = f & 7, c = g << 3;
    long long row = br ? ((long long)k * NTOK + j) : ((long long)j * NTOK + k);
    u16x8 v = *(const u16x8*)&Ybf[row * YBC + vb + c];
    #pragma unroll
    for (int m = 0; m < 8; ++m) { int mm = (m + g) & 7; Vt[c + mm][k] = v[mm]; }
  }
  __syncthreads();

  // ---- QK^T: S[i=quad*4+r][kt=n*16+l15] in registers ----
  f32x4 acc[10];
  #pragma unroll
  for (int n = 0; n < 10; ++n) acc[n] = (f32x4){0.f,0.f,0.f,0.f};
  #pragma unroll
  for (int n = 0; n < 10; ++n) {
    acc[n] = __builtin_amdgcn_mfma_f32_16x16x32_bf16(a0, *(const bf16x8*)&Kl[n*16 + l15][quad*8],      acc[n], 0,0,0);
    acc[n] = __builtin_amdgcn_mfma_f32_16x16x32_bf16(a1, *(const bf16x8*)&Kl[n*16 + l15][32 + quad*8], acc[n], 0,0,0);
  }
  __syncthreads();   // Kl dead; its space becomes Pl

  // ---- softmax (sum-only, base-2: Q and E pre-scaled by log2e) ----
  float sum[4] = {0.f, 0.f, 0.f, 0.f};
  const unsigned int* bgh = bg + (long long)h * NNR + (long long)i0 * NTOK;
  #pragma unroll
  for (int n = 0; n < 10; ++n) {
    #pragma unroll
    for (int r = 0; r < 4; ++r) {
      unsigned int u = bgh[(quad * 4 + r) * NTOK + n * 16 + l15];
      float bias = h2f((unsigned short)(u & 0xFFFFu));
      float gate = h2f((unsigned short)(u >> 16));
      float q = exp2f(acc[n][r] + bias);
      sum[r] += q;
      Pl[wv * 16 + quad * 4 + r][n * 16 + l15] = bf16_rne(q * gate);
    }
  }
  #pragma unroll
  for (int r = 0; r < 4; ++r) {
    #pragma unroll
    for (int m = 1; m < 16; m <<= 1) sum[r] += __shfl_xor(sum[r], m, 64);
  }
  // ---- PV (wave-private Pl rows; no barrier needed) ----
  f32x4 o[4];
  #pragma unroll
  for (int dd = 0; dd < 4; ++dd) o[dd] = (f32x4){0.f,0.f,0.f,0.f};
  #pragma unroll
  for (int ks = 0; ks < 5; ++ks) {
    bf16x8 af = *(const bf16x8*)&Pl[wv * 16 + l15][ks * 32 + quad * 8];
    #pragma unroll
    for (int dd = 0; dd < 4; ++dd)
      o[dd] = __builtin_amdgcn_mfma_f32_16x16x32_bf16(af, *(const bf16x8*)&Vt[dd*16 + l15][ks*32 + quad*8], o[dd], 0,0,0);
  }
  float inv[4];
  #pragma unroll
  for (int r = 0; r < 4; ++r) inv[r] = 1.f / sum[r];
  #pragma unroll
  for (int dd = 0; dd < 4; ++dd)
    #pragma unroll
    for (int r = 0; r < 4; ++r)
      Vab[((long long)(i0 + quad*4 + r) * NTOK + j) * 512 + br*256 + h*64 + dd*16 + l15] =
          bf16_rne(o[dd][r] * inv[r]);
}

// ---------------- output GEMM (MFMA): out = Va @ WoT^T + bo ----------------
// 1D grid 800: m = d%400 (A-panel sharers spaced 400 -> same XCD), n = d/400
__global__ __launch_bounds__(256) void out_kernel(const unsigned short* __restrict__ Vab,
                                                  const unsigned short* __restrict__ WoT,
                                                  const float* __restrict__ bo,
                                                  float* __restrict__ out) {
  __shared__ unsigned short As[64][72];
  __shared__ unsigned short Bs[128][72];
  const int d = blockIdx.x;
  const int n0 = (d / 400) * 128;
  const int m0 = (d % 400) * 64;
  const int t = threadIdx.x;
  const int lane = t & 63, w = t >> 6;
  const int quad = lane >> 4, l15 = lane & 15;
  f32x4 acc[8];
  #pragma unroll
  for (int c = 0; c < 8; ++c) acc[c] = (f32x4){0.f,0.f,0.f,0.f};
  for (int k0 = 0; k0 < 512; k0 += 64) {
    #pragma unroll
    for (int p = 0; p < 2; ++p) {
      int f = t + p * 256;
      int row = f >> 3, c = (f & 7) << 3;
      *(u16x8*)&As[row][c] = *(const u16x8*)&Vab[(long long)(m0 + row) * 512 + k0 + c];
    }
    #pragma unroll
    for (int p = 0; p < 4; ++p) {
      int f = t + p * 256;
      int row = f >> 3, c = (f & 7) << 3;
      *(u16x8*)&Bs[row][c] = *(const u16x8*)&WoT[(long long)(n0 + row) * 512 + k0 + c];
    }
    __syncthreads();
    #pragma unroll
    for (int ks = 0; ks < 2; ++ks) {
      bf16x8 a0 = *(const bf16x8*)&As[w * 16 + l15][ks * 32 + quad * 8];
      #pragma unroll
      for (int nt = 0; nt < 8; ++nt) {
        bf16x8 bfr = *(const bf16x8*)&Bs[nt * 16 + l15][ks * 32 + quad * 8];
        acc[nt] = __builtin_amdgcn_mfma_f32_16x16x32_bf16(a0, bfr, acc[nt], 0, 0, 0);
      }
    }
    __syncthreads();
  }
  #pragma unroll
  for (int nt = 0; nt < 8; ++nt) {
    int col = n0 + nt * 16 + l15;
    float bias = bo[col];
    #pragma unroll
    for (int r = 0; r < 4; ++r) {
      long long row = m0 + w * 16 + quad * 4 + r;
      out[row * 256 + col] = acc[nt][r] + bias;
    }
  }
}

extern "C" void kernel_launch(void* const* d_in, const int* in_sizes, int n_in,
                              void* d_out, int out_size, void* d_ws, size_t ws_size,
                              hipStream_t stream) {
  const float* e       = (const float*)d_in[0];
  const float* mask    = (const float*)d_in[1];
  const float* ln_g    = (const float*)d_in[2];
  const float* ln_b    = (const float*)d_in[3];
  const float* Wq_in   = (const float*)d_in[4];
  const float* bq_in   = (const float*)d_in[5];
  const float* Wkv_in  = (const float*)d_in[6];
  const float* bkv_in  = (const float*)d_in[7];
  const float* Weg_in  = (const float*)d_in[8];
  const float* beg_in  = (const float*)d_in[9];
  const float* Wq_out  = (const float*)d_in[10];
  const float* bq_out  = (const float*)d_in[11];
  const float* Wkv_out = (const float*)d_in[12];
  const float* bkv_out = (const float*)d_in[13];
  const float* Weg_out = (const float*)d_in[14];
  const float* beg_out = (const float*)d_in[15];
  const float* Wo      = (const float*)d_in[16];
  const float* bo      = (const float*)d_in[17];

  float* ws = (float*)d_ws;
  unsigned short* elnbf = (unsigned short*)(ws + OFF_ELN);
  unsigned short* Ybf   = (unsigned short*)(ws + OFF_YBF);
  unsigned short* WpT   = (unsigned short*)(ws + OFF_WPT);
  float* bp             = ws + OFF_BP;
  unsigned short* WoT   = (unsigned short*)(ws + OFF_WOT);
  unsigned short* bgIn  = (unsigned short*)(ws + OFF_BGI);
  unsigned short* bgOut = (unsigned short*)(ws + OFF_BGO);
  unsigned short* Vab   = (unsigned short*)(ws + OFF_VAB);
  float* outp = (float*)d_out;

  hipLaunchKernelGGL(prep_kernel, dim3(LN_BLOCKS + PACK_BLOCKS), dim3(256), 0, stream,
                     e, ln_g, ln_b, elnbf,
                     Wq_in, bq_in, Wkv_in, bkv_in, Weg_in, beg_in,
                     Wq_out, bq_out, Wkv_out, bkv_out, Weg_out, beg_out, Wo,
                     WpT, bp, WoT);
  hipLaunchKernelGGL(proj_kernel, dim3(1400), dim3(256), 0, stream, elnbf, WpT, bp, mask,
                     Ybf, bgIn, bgOut);
  hipLaunchKernelGGL(attn_kernel, dim3(1600), dim3(512), 0, stream, Ybf,
                     (const unsigned int*)bgIn, (const unsigned int*)bgOut, Vab);
  hipLaunchKernelGGL(out_kernel, dim3(800), dim3(256), 0, stream, Vab, WoT, bo, outp);
}